// Round 3
// baseline (478.160 us; speedup 1.0000x reference)
//
#include <hip/hip_runtime.h>

#define NTOP 256

typedef __attribute__((ext_vector_type(8))) short bf16x8;
typedef __attribute__((ext_vector_type(4))) float f32x4;

// round-to-nearest-even split of fp32 into bf16 hi/lo, packed (hi<<16)|lo
__device__ inline unsigned int packbf(float x) {
  unsigned int u = __float_as_uint(x);
  unsigned int r = (u + 0x7fffu + ((u >> 16) & 1u)) & 0xffff0000u;
  float res = x - __uint_as_float(r);
  unsigned int u2 = __float_as_uint(res);
  unsigned int r2 = u2 + 0x7fffu + ((u2 >> 16) & 1u);
  return r | (r2 >> 16);
}

__device__ inline float tanh_fast(float x) {
  float e = __expf(2.f * x);
  return 1.f - 2.f / (e + 1.f);
}

template <int CTRL>
__device__ inline float dpp_f(float v) {
  return __int_as_float(__builtin_amdgcn_update_dpp(
      0, __float_as_int(v), CTRL, 0xf, 0xf, true));
}

// inclusive prefix sum within each 16-lane row
__device__ inline float scan16(float v) {
  float s = v;
  s += dpp_f<0x111>(s);  // row_shr:1
  s += dpp_f<0x112>(s);  // row_shr:2
  s += dpp_f<0x114>(s);  // row_shr:4
  s += dpp_f<0x118>(s);  // row_shr:8
  return s;
}

// ---------------------------------------------------------------- K1
// 1024 threads, 16 waves. Wave w owns k-slice [16w,16w+16); lane l owns
// output quad [4l,4l+4). h-slice reads are single-address broadcasts.
// Cross-k reduce: partial quads -> LDS, quad-lane DPP sum, tanh by 1 lane.
__global__ __launch_bounds__(1024, 4) void rsbc_recur(
    const float* __restrict__ Wih, const float* __restrict__ Whh,
    const float* __restrict__ bih, const float* __restrict__ bhh,
    const float* __restrict__ h0, unsigned int* __restrict__ Hpack) {
  __shared__ __align__(16) float hsh[NTOP];
  __shared__ __align__(16) float pw[16 * 260];
  const int tid = threadIdx.x;
  const int w = tid >> 6, l = tid & 63;
  const int jr = tid >> 2, p4 = tid & 3;     // reduce-phase assignment
  const float bj = bih[jr] + bhh[jr];

  // L[4c+g] = W[4l+c][16w+4g .. +4]  (W_ih first, Wc after step 0)
  float4 L[16];
#pragma unroll
  for (int c = 0; c < 4; ++c)
#pragma unroll
    for (int g = 0; g < 4; ++g)
      L[4 * c + g] = *reinterpret_cast<const float4*>(
          Wih + (4 * l + c) * NTOP + 16 * w + 4 * g);

  if (tid < NTOP) hsh[tid] = h0[tid];
  __syncthreads();

#pragma unroll 1
  for (int s = 0; s < 255; ++s) {
    float4 hv[4];
#pragma unroll
    for (int g = 0; g < 4; ++g)
      hv[g] = *reinterpret_cast<const float4*>(hsh + 16 * w + 4 * g);
    float a[4] = {0.f, 0.f, 0.f, 0.f};
#pragma unroll
    for (int c = 0; c < 4; ++c)
#pragma unroll
      for (int g = 0; g < 4; ++g) {
        a[c] += hv[g].x * L[4 * c + g].x;
        a[c] += hv[g].y * L[4 * c + g].y;
        a[c] += hv[g].z * L[4 * c + g].z;
        a[c] += hv[g].w * L[4 * c + g].w;
      }
    *reinterpret_cast<float4*>(&pw[w * 260 + 4 * l]) =
        make_float4(a[0], a[1], a[2], a[3]);
    __syncthreads();
    // reduce: thread (jr,p4) sums partials 4p4..4p4+3 for output jr
    float v = pw[(4 * p4 + 0) * 260 + jr] + pw[(4 * p4 + 1) * 260 + jr] +
              pw[(4 * p4 + 2) * 260 + jr] + pw[(4 * p4 + 3) * 260 + jr];
    v += dpp_f<0xB1>(v);  // quad_perm(1,0,3,2)
    v += dpp_f<0x4E>(v);  // quad_perm(2,3,0,1)
    if (p4 == 0) {
      float hn = tanh_fast(v + bj);
      hsh[jr] = hn;
      Hpack[s * NTOP + jr] = packbf(hn);
    }
    __syncthreads();
    if (s == 0) {  // build Wc = W_ih + W_hh after step 0
#pragma unroll
      for (int c = 0; c < 4; ++c)
#pragma unroll
        for (int g = 0; g < 4; ++g) {
          float4 t = *reinterpret_cast<const float4*>(
              Whh + (4 * l + c) * NTOP + 16 * w + 4 * g);
          L[4 * c + g].x += t.x; L[4 * c + g].y += t.y;
          L[4 * c + g].z += t.z; L[4 * c + g].w += t.w;
        }
    }
  }
}

// ---------------------------------------------------------------- K2
// bf16x3 MFMA GEMM (Z @ H^T) + sigmoid + log-space stick-breaking.
// 512 threads (8 waves 2x4), BM=128, N=256, K-chunk=32 (8 chunks).
// LDS: A[128][hi32|lo32 bf16] 16KB + B[256][...] 32KB, XOR-swizzled.
// Epilogue in registers: sp=softplus, DPP scan16 prefix, rowT cross-wave
// fixup, out = zc*exp(-Slocal)*exp(-W); direct reg->global store.
__global__ __launch_bounds__(512, 4) void rsbc_gemm_sb(
    const float* __restrict__ z, const unsigned int* __restrict__ Hpack,
    float* __restrict__ out) {
  __shared__ __align__(16) char smem[49152];
  __shared__ float logtab[NTOP];
  __shared__ float rowT[128 * 5];
  char* Ab = smem;            // A plane: 128 rows x 128 B
  char* Bb = smem + 16384;    // B plane: 256 rows x 128 B

  const int tid = threadIdx.x;
  const size_t row0 = (size_t)blockIdx.x * 128;
  const int wid = tid >> 6, lane = tid & 63;
  const int wr = wid >> 2, wc = wid & 3;
  const int l15 = lane & 15, l4 = lane >> 4;

  if (tid < NTOP) logtab[tid] = (tid < 255) ? __logf((float)(255 - tid)) : 0.f;

  f32x4 acc[4][4];
#pragma unroll
  for (int mt = 0; mt < 4; ++mt)
#pragma unroll
    for (int nt = 0; nt < 4; ++nt) acc[mt][nt] = (f32x4){0.f, 0.f, 0.f, 0.f};

  for (int kc = 0; kc < 8; ++kc) {
    const int kb = kc * 32;
    // ---- global loads to regs (before barrier: overlap prev compute)
    float4 zreg[2];
#pragma unroll
    for (int it = 0; it < 2; ++it) {
      int idx = tid + 512 * it;         // 0..1023
      int r = idx >> 3, q = idx & 7;    // r 0..127
      zreg[it] = *reinterpret_cast<const float4*>(
          z + (row0 + r) * NTOP + kb + 4 * q);
    }
    uint4 hreg[4];
#pragma unroll
    for (int it = 0; it < 4; ++it) {
      int idx = tid + 512 * it;         // 0..2047
      int r = idx >> 3, q = idx & 7;    // r 0..255
      hreg[it] = (r < 255) ? *reinterpret_cast<const uint4*>(
                                 Hpack + r * NTOP + kb + 4 * q)
                           : make_uint4(0u, 0u, 0u, 0u);
    }
    __syncthreads();                    // prev chunk frag reads done
    // ---- split/unpack + swizzled LDS writes
#pragma unroll
    for (int it = 0; it < 2; ++it) {
      int idx = tid + 512 * it;
      int r = idx >> 3, q = idx & 7;
      int sw = (r & 7) << 4;
      float4 v = zreg[it];
      unsigned int p0 = packbf(v.x), p1 = packbf(v.y),
                   p2 = packbf(v.z), p3 = packbf(v.w);
      *reinterpret_cast<ushort4*>(Ab + r * 128 + ((8 * q) ^ sw)) =
          make_ushort4((ushort)(p0 >> 16), (ushort)(p1 >> 16),
                       (ushort)(p2 >> 16), (ushort)(p3 >> 16));
      *reinterpret_cast<ushort4*>(Ab + r * 128 + ((64 + 8 * q) ^ sw)) =
          make_ushort4((ushort)(p0 & 0xffff), (ushort)(p1 & 0xffff),
                       (ushort)(p2 & 0xffff), (ushort)(p3 & 0xffff));
    }
#pragma unroll
    for (int it = 0; it < 4; ++it) {
      int idx = tid + 512 * it;
      int r = idx >> 3, q = idx & 7;
      int sw = (r & 7) << 4;
      uint4 h = hreg[it];
      *reinterpret_cast<ushort4*>(Bb + r * 128 + ((8 * q) ^ sw)) =
          make_ushort4((ushort)(h.x >> 16), (ushort)(h.y >> 16),
                       (ushort)(h.z >> 16), (ushort)(h.w >> 16));
      *reinterpret_cast<ushort4*>(Bb + r * 128 + ((64 + 8 * q) ^ sw)) =
          make_ushort4((ushort)(h.x & 0xffff), (ushort)(h.y & 0xffff),
                       (ushort)(h.z & 0xffff), (ushort)(h.w & 0xffff));
    }
    __syncthreads();                    // staged
    // ---- fragments + 48 MFMA (one K=32 step)
    bf16x8 ah[4], al[4];
#pragma unroll
    for (int mt = 0; mt < 4; ++mt) {
      int r = 64 * wr + 16 * mt + l15;
      int sw = (r & 7) << 4;
      ah[mt] = *reinterpret_cast<const bf16x8*>(Ab + r * 128 + ((16 * l4) ^ sw));
      al[mt] = *reinterpret_cast<const bf16x8*>(
          Ab + r * 128 + ((64 + 16 * l4) ^ sw));
    }
#pragma unroll
    for (int nt = 0; nt < 4; ++nt) {
      int n = 64 * wc + 16 * nt + l15;
      int sw = (n & 7) << 4;
      bf16x8 bh = *reinterpret_cast<const bf16x8*>(
          Bb + n * 128 + ((16 * l4) ^ sw));
      bf16x8 bl = *reinterpret_cast<const bf16x8*>(
          Bb + n * 128 + ((64 + 16 * l4) ^ sw));
#pragma unroll
      for (int mt = 0; mt < 4; ++mt) {
        acc[mt][nt] = __builtin_amdgcn_mfma_f32_16x16x32_bf16(
            ah[mt], bh, acc[mt][nt], 0, 0, 0);
        acc[mt][nt] = __builtin_amdgcn_mfma_f32_16x16x32_bf16(
            ah[mt], bl, acc[mt][nt], 0, 0, 0);
        acc[mt][nt] = __builtin_amdgcn_mfma_f32_16x16x32_bf16(
            al[mt], bh, acc[mt][nt], 0, 0, 0);
      }
    }
  }

  // ---- epilogue pass A: zc, sp=softplus, in-register prefix scan
  // C layout: row = 64wr+16mt+4*l4+i, col = 64wc+16nt+l15
  float lt[4];
#pragma unroll
  for (int nt = 0; nt < 4; ++nt) lt[nt] = logtab[64 * wc + 16 * nt + l15];
#pragma unroll
  for (int mt = 0; mt < 4; ++mt)
#pragma unroll
    for (int i = 0; i < 4; ++i) {
      float carry = 0.f;
#pragma unroll
      for (int nt = 0; nt < 4; ++nt) {
        float a = acc[mt][nt][i];
        float t1 = __expf(-a);
        float s1 = __builtin_amdgcn_rcpf(1.f + t1);   // sigmoid(logit)
        float x = s1 - lt[nt];
        float t = __expf(-x);
        float zc = __builtin_amdgcn_rcpf(1.f + t);    // sigmoid(x)
        float sp = x + __logf(1.f + t);               // softplus(x)
        if ((wc == 3) && (nt == 3) && (l15 == 15)) {  // col 255 dummy
          zc = 1.f; sp = 0.f;
        }
        float incl = scan16(sp);
        float Sl = carry + (incl - sp);               // exclusive prefix
        acc[mt][nt][i] = zc * __expf(-Sl);
        carry += __shfl(incl, 15, 16);
      }
      if (l15 == 0)
        rowT[(64 * wr + 16 * mt + 4 * l4 + i) * 5 + wc] = carry;
    }
  __syncthreads();

  // ---- pass B: cross-wave offset + direct global store
#pragma unroll
  for (int mt = 0; mt < 4; ++mt)
#pragma unroll
    for (int i = 0; i < 4; ++i) {
      int r = 64 * wr + 16 * mt + 4 * l4 + i;
      float ew = 1.f;
      if (wc > 0) {
        float W = rowT[r * 5 + 0];
        if (wc > 1) W += rowT[r * 5 + 1];
        if (wc > 2) W += rowT[r * 5 + 2];
        ew = __expf(-W);
      }
      float* op = out + (row0 + r) * NTOP + 64 * wc + l15;
#pragma unroll
      for (int nt = 0; nt < 4; ++nt) op[16 * nt] = acc[mt][nt][i] * ew;
    }
}

// ---------------------------------------------------------------- launch
extern "C" void kernel_launch(void* const* d_in, const int* in_sizes, int n_in,
                              void* d_out, int out_size, void* d_ws, size_t ws_size,
                              hipStream_t stream) {
  const float* z   = (const float*)d_in[0];
  const float* h0  = (const float*)d_in[1];
  const float* Wih = (const float*)d_in[2];
  const float* Whh = (const float*)d_in[3];
  const float* bih = (const float*)d_in[4];
  const float* bhh = (const float*)d_in[5];
  float* out = (float*)d_out;
  unsigned int* Hpack = (unsigned int*)d_ws;  // 255*256 uint32

  rsbc_recur<<<1, 1024, 0, stream>>>(Wih, Whh, bih, bhh, h0, Hpack);
  const int nrows = out_size / NTOP;          // 131072
  const int blocks = nrows / 128;             // 1024
  rsbc_gemm_sb<<<blocks, 512, 0, stream>>>(z, Hpack, out);
}